// Round 3
// baseline (417.871 us; speedup 1.0000x reference)
//
#include <hip/hip_runtime.h>
#include <hip/hip_bf16.h>

// B=2,S=2048 -> T=4096 tokens, D=1024, H=2048, E=8, top_k=2
#define TOK 4096
#define DD 1024
#define HH 2048
#define NE 8
#define RTOT (TOK * 2)

typedef __attribute__((ext_vector_type(8))) short bf16x8;
typedef __attribute__((ext_vector_type(4))) float f32x4;

static __device__ __forceinline__ unsigned short f2bf(float f) {
  union { float f; unsigned int u; } v; v.f = f;
  unsigned int r = v.u + 0x7fffu + ((v.u >> 16) & 1u);
  return (unsigned short)(r >> 16);
}

// async global->LDS, 16B/lane; LDS dest = wave-uniform base + lane*16
static __device__ __forceinline__ void gload16(const unsigned short* g, unsigned short* l) {
  __builtin_amdgcn_global_load_lds(
      (const __attribute__((address_space(1))) unsigned int*)g,
      (__attribute__((address_space(3))) unsigned int*)l, 16, 0, 0);
}

#define FENCE() asm volatile("" ::: "memory")
#define BARX() do { FENCE(); __builtin_amdgcn_s_barrier(); FENCE(); } while (0)
#define WAITV0() asm volatile("s_waitcnt vmcnt(0)" ::: "memory")
#define WAITL0() asm volatile("s_waitcnt lgkmcnt(0)" ::: "memory")

// ---------------- router ----------------
__global__ void router_k(const float* __restrict__ x, const float* __restrict__ gw,
                         int* __restrict__ topi, float* __restrict__ topp,
                         int* __restrict__ counts) {
  const int lane = threadIdx.x & 63;
  const int t = blockIdx.x * 4 + (threadIdx.x >> 6);
  const float4* xr = (const float4*)(x + (size_t)t * DD);
  float acc[NE];
#pragma unroll
  for (int e = 0; e < NE; ++e) acc[e] = 0.f;
#pragma unroll
  for (int i = 0; i < 4; ++i) {
    const float4 xv = xr[i * 64 + lane];
#pragma unroll
    for (int e = 0; e < NE; ++e) {
      const float4 gv = ((const float4*)(gw + (size_t)e * DD))[i * 64 + lane];
      acc[e] += xv.x * gv.x + xv.y * gv.y + xv.z * gv.z + xv.w * gv.w;
    }
  }
#pragma unroll
  for (int e = 0; e < NE; ++e)
#pragma unroll
    for (int s = 32; s > 0; s >>= 1) acc[e] += __shfl_xor(acc[e], s, 64);
  if (lane == 0) {
    int i0 = 0; float v0 = acc[0];
#pragma unroll
    for (int e = 1; e < NE; ++e) if (acc[e] > v0) { v0 = acc[e]; i0 = e; }
    int i1 = -1; float v1 = -1e30f;
#pragma unroll
    for (int e = 0; e < NE; ++e) if (e != i0 && acc[e] > v1) { v1 = acc[e]; i1 = e; }
    const float ex = __expf(v1 - v0);
    const float inv = 1.f / (1.f + ex);
    topi[t * 2] = i0; topi[t * 2 + 1] = i1;
    topp[t * 2] = inv; topp[t * 2 + 1] = ex * inv;
    atomicAdd(&counts[i0], 1); atomicAdd(&counts[i1], 1);
  }
}

// ---------------- x fp32 -> bf16 ----------------
__global__ void convert_k(const float* __restrict__ x, unsigned short* __restrict__ xb) {
  const int i = blockIdx.x * 256 + threadIdx.x;
  const float4 v = ((const float4*)x)[i];
  ushort4 o;
  o.x = f2bf(v.x); o.y = f2bf(v.y); o.z = f2bf(v.z); o.w = f2bf(v.w);
  ((ushort4*)xb)[i] = o;
}

// ---------------- scan / scatter ----------------
__global__ void scan_k(const int* __restrict__ counts, int* __restrict__ offsets,
                       int* __restrict__ cursor) {
  if (threadIdx.x == 0) {
    int s = 0;
    for (int e = 0; e < NE; ++e) { offsets[e] = s; cursor[e] = s; s += counts[e]; }
  }
}

__global__ void scatter_k(const int* __restrict__ topi, const float* __restrict__ topp,
                          int* __restrict__ cursor, int* __restrict__ perm,
                          float* __restrict__ prow, int* __restrict__ rowid) {
  const int t = blockIdx.x * 256 + threadIdx.x;
#pragma unroll
  for (int k = 0; k < 2; ++k) {
    const int e = topi[t * 2 + k];
    const int pos = atomicAdd(&cursor[e], 1);
    perm[pos] = t;
    prow[pos] = topp[t * 2 + k];
    rowid[t * 2 + k] = pos;
  }
}

// ---------------- GEMM1: X(gathered,bf16) @ [w1|w2](fp32, staged in-kernel) -> h ----------------
// BM=256, BN=256 (interleaved G/U by 16 cols -> 128 h-cols), BK=64, 8 waves (2Mx4N).
// Depth-2 LDS double-buffer, 1 barrier per K-tile, vmcnt(0) after compute (T14).
__global__ __launch_bounds__(512, 2) void gemm1_k(
    const unsigned short* __restrict__ Xb, const float* __restrict__ w1,
    const float* __restrict__ w2, const int* __restrict__ counts,
    const int* __restrict__ offsets, const int* __restrict__ perm,
    unsigned short* __restrict__ hbuf) {
  const int e = blockIdx.z;
  const int ne = counts[e];
  const int m0 = blockIdx.y * 256;
  if (m0 >= ne) return;
  const int off = offsets[e];
  const int jb = blockIdx.x * 128;   // h-col base (this block covers 128 h-cols)

  extern __shared__ __align__(16) unsigned short lds[];
  // As: [0,16384) + b*16384 ; Bs: 32768 + b*16384 (shorts)

  const int tid = threadIdx.x;
  const int lane = tid & 63, wv = tid >> 6;

  // A staging: wave wv stages rows [wv*32, wv*32+32), 4 gloads; XOR-swizzled source
  const int lrow8 = lane >> 3;
  const int schunk = ((lane & 7) ^ lrow8) * 8;
  const unsigned short* pA[4];
#pragma unroll
  for (int q = 0; q < 4; ++q) {
    const int row = wv * 32 + q * 8 + lrow8;
    const int g = perm[off + min(m0 + row, ne - 1)];
    pA[q] = Xb + (size_t)g * DD + schunk;
  }

  // B staging: thread -> 4 LDS rows r=4*nq..+3 (interleaved w1/w2 16-col groups), k-chunk c=wv
  const int nq = tid & 63;
  const int r0b = nq * 4;
  const int bmat = (r0b >> 4) & 1;                       // 0 -> w1 (G), 1 -> w2 (U)
  const int jsrc = jb + (r0b >> 5) * 16 + (r0b & 15);    // source h-col
  const float* pB = (bmat ? w2 : w1) + ((size_t)e * DD + wv * 8) * HH + jsrc;
  int bslot[4];
#pragma unroll
  for (int i = 0; i < 4; ++i) {
    const int r = r0b + i;
    bslot[i] = r * 64 + ((wv ^ (r & 7) ^ ((r >> 3) & 7)) * 8);
  }

  const int wr = wv >> 2, wc = wv & 3;
  const int lr = lane & 15, kc = lane >> 4;
  const int skA[2] = { ((kc) ^ (lr & 7)) * 8, ((4 + kc) ^ (lr & 7)) * 8 };
  int skB[2][4];
#pragma unroll
  for (int kk = 0; kk < 2; ++kk)
#pragma unroll
    for (int nf = 0; nf < 4; ++nf)
      skB[kk][nf] = ((kk * 4 + kc) ^ (lr & 7) ^ (nf * 2 + (lr >> 3))) * 8;

  f32x4 acc[8][4];
#pragma unroll
  for (int a = 0; a < 8; ++a)
#pragma unroll
    for (int b = 0; b < 4; ++b) acc[a][b] = f32x4{0.f, 0.f, 0.f, 0.f};

  float4 bv[8];
  auto issueA = [&](int b) {
#pragma unroll
    for (int q = 0; q < 4; ++q) {
      gload16(pA[q], lds + b * 16384 + (wv * 32 + q * 8) * 64);
      pA[q] += 64;
    }
  };
  auto issueB = [&]() {
#pragma unroll
    for (int jj = 0; jj < 8; ++jj) bv[jj] = *(const float4*)(pB + (size_t)jj * HH);
    pB += (size_t)64 * HH;
  };
  auto writeB = [&](int b) {
#pragma unroll
    for (int i = 0; i < 4; ++i) {
      union { unsigned short u[8]; uint4 v; } pk;
#pragma unroll
      for (int jj = 0; jj < 8; ++jj) pk.u[jj] = f2bf((&bv[jj].x)[i]);
      *(uint4*)&lds[32768 + b * 16384 + bslot[i]] = pk.v;
    }
  };
  auto compute = [&](int b) {
    const unsigned short* Ab = lds + b * 16384;
    const unsigned short* Bb = lds + 32768 + b * 16384;
#pragma unroll
    for (int kk = 0; kk < 2; ++kk) {
      bf16x8 af[8], bf[4];
#pragma unroll
      for (int mf = 0; mf < 8; ++mf)
        af[mf] = *(const bf16x8*)&Ab[(wr * 128 + mf * 16 + lr) * 64 + skA[kk]];
#pragma unroll
      for (int nf = 0; nf < 4; ++nf)
        bf[nf] = *(const bf16x8*)&Bb[(wc * 64 + nf * 16 + lr) * 64 + skB[kk][nf]];
#pragma unroll
      for (int mf = 0; mf < 8; ++mf)
#pragma unroll
        for (int nf = 0; nf < 4; ++nf)
          acc[mf][nf] = __builtin_amdgcn_mfma_f32_16x16x32_bf16(af[mf], bf[nf], acc[mf][nf], 0, 0, 0);
    }
  };

  // prologue: stage tile 0
  issueB(); issueA(0);
  WAITV0(); writeB(0); WAITL0(); BARX();
  for (int t = 0; t < DD / 64; ++t) {
    const int cur = t & 1;
    if (t < DD / 64 - 1) { issueB(); issueA(cur ^ 1); }
    compute(cur);
    if (t < DD / 64 - 1) { WAITV0(); writeB(cur ^ 1); }
    WAITL0(); BARX();
  }

  // epilogue: silu(g)*u, write h
#pragma unroll
  for (int mf = 0; mf < 8; ++mf)
#pragma unroll
    for (int p = 0; p < 2; ++p) {
      const f32x4 g = acc[mf][2 * p], u = acc[mf][2 * p + 1];
      const int hcol = jb + wc * 32 + p * 16 + lr;
#pragma unroll
      for (int r = 0; r < 4; ++r) {
        const int rl = m0 + wr * 128 + mf * 16 + kc * 4 + r;
        if (rl < ne) {
          const float gg = g[r], uu = u[r];
          const float hv = gg / (1.f + __expf(-gg)) * uu;
          hbuf[(size_t)(off + rl) * HH + hcol] = f2bf(hv);
        }
      }
    }
}

// ---------------- GEMM2: h(bf16) @ w3(fp32, staged in-kernel) * prob -> y fp32 ----------------
// BM=128, BN=256, BK=64, 8 waves (2Mx4N), same pipeline.
__global__ __launch_bounds__(512, 2) void gemm2_k(
    const unsigned short* __restrict__ hbuf, const float* __restrict__ w3,
    const int* __restrict__ counts, const int* __restrict__ offsets,
    const float* __restrict__ prow, float* __restrict__ ybuf) {
  const int e = blockIdx.z;
  const int ne = counts[e];
  const int m0 = blockIdx.y * 128;
  if (m0 >= ne) return;
  const int off = offsets[e];
  const int n1 = blockIdx.x * 256;

  extern __shared__ __align__(16) unsigned short lds[];
  // As: b*8192 ; Bs: 16384 + b*16384 (shorts)

  const int tid = threadIdx.x;
  const int lane = tid & 63, wv = tid >> 6;

  const int lrow8 = lane >> 3;
  const int schunk = ((lane & 7) ^ lrow8) * 8;
  const unsigned short* pA[2];
#pragma unroll
  for (int q = 0; q < 2; ++q) {
    const int row = wv * 16 + q * 8 + lrow8;
    pA[q] = hbuf + (size_t)(off + min(m0 + row, ne - 1)) * HH + schunk;
  }

  const int nq = tid & 63;
  const int r0b = nq * 4;                      // 4 consecutive d-cols
  const float* pB = w3 + ((size_t)e * HH + wv * 8) * DD + n1 + r0b;
  int bslot[4];
#pragma unroll
  for (int i = 0; i < 4; ++i) {
    const int r = r0b + i;
    bslot[i] = r * 64 + ((wv ^ (r & 7) ^ ((r >> 3) & 7)) * 8);
  }

  const int wr = wv >> 2, wc = wv & 3;
  const int lr = lane & 15, kc = lane >> 4;
  const int skA[2] = { ((kc) ^ (lr & 7)) * 8, ((4 + kc) ^ (lr & 7)) * 8 };
  int skB[2][4];
#pragma unroll
  for (int kk = 0; kk < 2; ++kk)
#pragma unroll
    for (int nf = 0; nf < 4; ++nf)
      skB[kk][nf] = ((kk * 4 + kc) ^ (lr & 7) ^ (nf * 2 + (lr >> 3))) * 8;

  f32x4 acc[4][4];
#pragma unroll
  for (int a = 0; a < 4; ++a)
#pragma unroll
    for (int b = 0; b < 4; ++b) acc[a][b] = f32x4{0.f, 0.f, 0.f, 0.f};

  float4 bv[8];
  auto issueA = [&](int b) {
#pragma unroll
    for (int q = 0; q < 2; ++q) {
      gload16(pA[q], lds + b * 8192 + (wv * 16 + q * 8) * 64);
      pA[q] += 64;
    }
  };
  auto issueB = [&]() {
#pragma unroll
    for (int jj = 0; jj < 8; ++jj) bv[jj] = *(const float4*)(pB + (size_t)jj * DD);
    pB += (size_t)64 * DD;
  };
  auto writeB = [&](int b) {
#pragma unroll
    for (int i = 0; i < 4; ++i) {
      union { unsigned short u[8]; uint4 v; } pk;
#pragma unroll
      for (int jj = 0; jj < 8; ++jj) pk.u[jj] = f2bf((&bv[jj].x)[i]);
      *(uint4*)&lds[16384 + b * 16384 + bslot[i]] = pk.v;
    }
  };
  auto compute = [&](int b) {
    const unsigned short* Ab = lds + b * 8192;
    const unsigned short* Bb = lds + 16384 + b * 16384;
#pragma unroll
    for (int kk = 0; kk < 2; ++kk) {
      bf16x8 af[4], bf[4];
#pragma unroll
      for (int mf = 0; mf < 4; ++mf)
        af[mf] = *(const bf16x8*)&Ab[(wr * 64 + mf * 16 + lr) * 64 + skA[kk]];
#pragma unroll
      for (int nf = 0; nf < 4; ++nf)
        bf[nf] = *(const bf16x8*)&Bb[(wc * 64 + nf * 16 + lr) * 64 + skB[kk][nf]];
#pragma unroll
      for (int mf = 0; mf < 4; ++mf)
#pragma unroll
        for (int nf = 0; nf < 4; ++nf)
          acc[mf][nf] = __builtin_amdgcn_mfma_f32_16x16x32_bf16(af[mf], bf[nf], acc[mf][nf], 0, 0, 0);
    }
  };

  issueB(); issueA(0);
  WAITV0(); writeB(0); WAITL0(); BARX();
  for (int t = 0; t < HH / 64; ++t) {
    const int cur = t & 1;
    if (t < HH / 64 - 1) { issueB(); issueA(cur ^ 1); }
    compute(cur);
    if (t < HH / 64 - 1) { WAITV0(); writeB(cur ^ 1); }
    WAITL0(); BARX();
  }

#pragma unroll
  for (int mf = 0; mf < 4; ++mf)
#pragma unroll
    for (int nf = 0; nf < 4; ++nf)
#pragma unroll
      for (int r = 0; r < 4; ++r) {
        const int rl = m0 + wr * 64 + mf * 16 + kc * 4 + r;
        if (rl < ne) {
          ybuf[(size_t)(off + rl) * DD + n1 + wc * 64 + nf * 16 + lr] =
              prow[off + rl] * acc[mf][nf][r];
        }
      }
}

// ---------------- combine ----------------
__global__ void combine_k(const float* __restrict__ y, const int* __restrict__ rowid,
                          float* __restrict__ out) {
  const int i = blockIdx.x * 256 + threadIdx.x;
  const int t = i >> 8;
  const float4 a = ((const float4*)(y + (size_t)rowid[2 * t] * DD))[i & 255];
  const float4 b = ((const float4*)(y + (size_t)rowid[2 * t + 1] * DD))[i & 255];
  float4 o; o.x = a.x + b.x; o.y = a.y + b.y; o.z = a.z + b.z; o.w = a.w + b.w;
  ((float4*)out)[i] = o;
}

// ---------------- workspace layout ----------------
#define WS_COUNTS 0
#define WS_OFFS 32
#define WS_CURS 64
#define WS_TOPI 128
#define WS_TOPP (WS_TOPI + TOK * 2 * 4)
#define WS_ROWID (WS_TOPP + TOK * 2 * 4)
#define WS_PERM (WS_ROWID + TOK * 2 * 4)
#define WS_PROW (WS_PERM + RTOT * 4)
#define WS_XB ((WS_PROW + RTOT * 4 + 255) & ~(size_t)255)
#define WS_H (WS_XB + (size_t)TOK * DD * 2)
#define WS_Y (WS_H + (size_t)RTOT * HH * 2)
// end = WS_Y + RTOT*DD*4 ~= 73 MB

extern "C" void kernel_launch(void* const* d_in, const int* in_sizes, int n_in,
                              void* d_out, int out_size, void* d_ws, size_t ws_size,
                              hipStream_t stream) {
  const float* x = (const float*)d_in[0];
  const float* gw = (const float*)d_in[1];
  const float* w1 = (const float*)d_in[2];
  const float* w2 = (const float*)d_in[3];
  const float* w3 = (const float*)d_in[4];
  float* out = (float*)d_out;
  char* ws = (char*)d_ws;

  int* counts = (int*)(ws + WS_COUNTS);
  int* offsets = (int*)(ws + WS_OFFS);
  int* cursor = (int*)(ws + WS_CURS);
  int* topi = (int*)(ws + WS_TOPI);
  float* topp = (float*)(ws + WS_TOPP);
  int* rowid = (int*)(ws + WS_ROWID);
  int* perm = (int*)(ws + WS_PERM);
  float* prow = (float*)(ws + WS_PROW);
  unsigned short* Xb = (unsigned short*)(ws + WS_XB);
  unsigned short* hbuf = (unsigned short*)(ws + WS_H);
  float* ybuf = (float*)(ws + WS_Y);

  hipFuncSetAttribute((const void*)gemm1_k, hipFuncAttributeMaxDynamicSharedMemorySize, 131072);
  hipFuncSetAttribute((const void*)gemm2_k, hipFuncAttributeMaxDynamicSharedMemorySize, 98304);

  hipMemsetAsync(ws, 0, 128, stream);
  router_k<<<TOK / 4, 256, 0, stream>>>(x, gw, topi, topp, counts);
  convert_k<<<TOK * DD / 4 / 256, 256, 0, stream>>>(x, Xb);
  scan_k<<<1, 64, 0, stream>>>(counts, offsets, cursor);
  scatter_k<<<TOK / 256, 256, 0, stream>>>(topi, topp, cursor, perm, prow, rowid);
  gemm1_k<<<dim3(2 * HH / 256, RTOT / 256, NE), 512, 131072, stream>>>(
      Xb, w1, w2, counts, offsets, perm, hbuf);
  gemm2_k<<<dim3(DD / 256, RTOT / 128, NE), 512, 98304, stream>>>(
      hbuf, w3, counts, offsets, prow, ybuf);
  combine_k<<<TOK * DD / 4 / 256, 256, 0, stream>>>(ybuf, rowid, out);
}